// Round 11
// baseline (588.961 us; speedup 1.0000x reference)
//
#include <hip/hip_runtime.h>

// NEAT batched forward — async-staged, persistent-block edition.
// Invariant across R3/R6/R9/R10: VALUBusy*dur ~ const, duty capped ~20% because
// each wave's phases chain on its own ~900cy global loads and __syncthreads
// drains vmcnt(0) (m97 analysis) so latency never hides. Fix:
//  - global_load_lds stages next genome's co/en/nl/in into LDS (compiler can't
//    sink it); ci/w go global->reg at genome start, covered by keys/scan work.
//  - raw s_barrier + lgkmcnt(0) only (no vmcnt drain) -> staging in flight
//    across the whole genome (T3/T4 counted-wait pattern).
//  - 37.7KB LDS -> 4 blocks/CU, 16 waves, all phases LDS/VALU-only.

#define NN    256
#define NE    4096
#define NIN   64
#define NOUT  8
#define NT    256
#define NWAVE 4
#define CAP   1728   // live edges: mean 1536, sd 31 -> 6.2 sigma
#define GPB   4      // genomes per block; grid = 4096/4 = 1024

__device__ __forceinline__ void gll16(const void* g, void* l) {
    __builtin_amdgcn_global_load_lds(
        (const __attribute__((address_space(1))) unsigned int*)g,
        (__attribute__((address_space(3))) unsigned int*)l, 16, 0, 0);
}
__device__ __forceinline__ void gll4(const void* g, void* l) {
    __builtin_amdgcn_global_load_lds(
        (const __attribute__((address_space(1))) unsigned int*)g,
        (__attribute__((address_space(3))) unsigned int*)l, 4, 0, 0);
}

// barrier that waits LDS ops only (restage global_load_lds stays in flight)
#define BAR_LGKM() do { \
    asm volatile("s_waitcnt lgkmcnt(0)" ::: "memory"); \
    __builtin_amdgcn_s_barrier(); \
    asm volatile("" ::: "memory"); \
} while (0)

// barrier that additionally drains this wave's staged loads (genome top)
#define BAR_ALL() do { \
    asm volatile("s_waitcnt vmcnt(0) lgkmcnt(0)" ::: "memory"); \
    __builtin_amdgcn_s_barrier(); \
    asm volatile("" ::: "memory"); \
} while (0)

__global__ __launch_bounds__(NT) void neat_fwd(
    const float* __restrict__ inputs,          // [B,64]
    const int*   __restrict__ node_layer,      // [B,256]
    const int*   __restrict__ conn_in,         // [B,4096]
    const int*   __restrict__ conn_out,        // [B,4096]
    const float* __restrict__ conn_w,          // [B,4096]
    const unsigned char* __restrict__ conn_en, // [B,4096] bool (layout sniffed)
    float*       __restrict__ out)             // [B,8]
{
    const int t    = threadIdx.x;
    const int wv   = t >> 6;
    const int lane = t & 63;
    const unsigned long long lmlt = (1ull << lane) - 1ull;
    const size_t g0 = (size_t)blockIdx.x * GPB;

    __shared__ int            s_co[NE];          // staged conn_out      16K
    __shared__ unsigned char  s_en[NE];          // staged conn_enabled   4K
    __shared__ int            s_nl[NN];          // staged node_layer     1K
    __shared__ float          s_in[NIN];         // staged inputs       256B
    __shared__ float          vals[NN];
    __shared__ float          agg[NN];
    __shared__ uint2          edges[CAP];        // {w, src|tgt<<8}    13.8K
    __shared__ int            wave_cnt[NWAVE][3];

    // --- sniff conn_enabled width (uniform): byte bools vs int32 ---
    const unsigned* en_sniff = (const unsigned*)conn_en;
    bool byte_mode = false;
#pragma unroll
    for (int i = 0; i < 16; ++i) byte_mode |= (en_sniff[i] > 1u);

    if (byte_mode) {
        // ---------------- fast path: async-staged pipeline ----------------
#define STAGE_ISSUE(GI) do { \
        const int* gco_ = conn_out + (GI) * NE; \
        gll16(gco_ + (0*256 + wv*64 + lane)*4, s_co + 0*1024 + wv*256); \
        gll16(gco_ + (1*256 + wv*64 + lane)*4, s_co + 1*1024 + wv*256); \
        gll16(gco_ + (2*256 + wv*64 + lane)*4, s_co + 2*1024 + wv*256); \
        gll16(gco_ + (3*256 + wv*64 + lane)*4, s_co + 3*1024 + wv*256); \
        gll16(conn_en + (GI)*NE + (wv*64 + lane)*16, s_en + wv*1024); \
        if (wv == 0) gll16(node_layer + (GI)*NN + lane*4, s_nl); \
        if (wv == 1) gll4 (inputs    + (GI)*NIN + lane,   s_in); \
    } while (0)

        STAGE_ISSUE(g0);   // prologue

#pragma unroll 1
        for (int g = 0; g < GPB; ++g) {
            const size_t gi = g0 + g;
            BAR_ALL();   // staged data for genome g ready & visible

            // issue ci/w global->reg loads (consumed at SCAT, ~1000cy later)
            const int4*   gci4 = (const int4*)(conn_in + gi * NE);
            const float4* gw4  = (const float4*)(conn_w + gi * NE);
            int4   ci0 = gci4[t];        int4   ci1 = gci4[NT + t];
            int4   ci2 = gci4[2*NT + t]; int4   ci3 = gci4[3*NT + t];
            float4 w0  = gw4[t];         float4 w1  = gw4[NT + t];
            float4 w2  = gw4[2*NT + t];  float4 w3  = gw4[3*NT + t];

            // init from staged LDS
            const int   nlT   = s_nl[t];
            const float vinit = (t < NIN) ? s_in[t] : 0.0f;
            vals[t] = vinit;
            agg[t]  = 0.0f;

            // keys: staged co/en + layer gather (all LDS)
            const int4*   s_co4 = (const int4*)s_co;
            const uchar4* s_en4 = (const uchar4*)s_en;
            int4   co0 = s_co4[t];        int4   co1 = s_co4[NT + t];
            int4   co2 = s_co4[2*NT + t]; int4   co3 = s_co4[3*NT + t];
            uchar4 e0  = s_en4[t];        uchar4 e1  = s_en4[NT + t];
            uchar4 e2  = s_en4[2*NT + t]; uchar4 e3  = s_en4[3*NT + t];

            unsigned keys = 0;
            int c1 = 0, c2 = 0, c3 = 0;
#define KEY1(J, COV, ENV) { \
            int k = (ENV) ? s_nl[(COV)] : 0; \
            keys |= (unsigned)k << (2*(J)); \
            c1 += (k == 1); c2 += (k == 2); c3 += (k == 3); }
            KEY1(0,  co0.x, e0.x) KEY1(1,  co0.y, e0.y) KEY1(2,  co0.z, e0.z) KEY1(3,  co0.w, e0.w)
            KEY1(4,  co1.x, e1.x) KEY1(5,  co1.y, e1.y) KEY1(6,  co1.z, e1.z) KEY1(7,  co1.w, e1.w)
            KEY1(8,  co2.x, e2.x) KEY1(9,  co2.y, e2.y) KEY1(10, co2.z, e2.z) KEY1(11, co2.w, e2.w)
            KEY1(12, co3.x, e3.x) KEY1(13, co3.y, e3.y) KEY1(14, co3.z, e3.z) KEY1(15, co3.w, e3.w)
#undef KEY1

#pragma unroll
            for (int off = 32; off > 0; off >>= 1) {
                c1 += __shfl_down(c1, off);
                c2 += __shfl_down(c2, off);
                c3 += __shfl_down(c3, off);
            }
            if (lane == 0) {
                wave_cnt[wv][0] = c1; wave_cnt[wv][1] = c2; wave_cnt[wv][2] = c3;
            }
            BAR_LGKM();   // wave_cnt + vals/agg visible; staged arrays fully consumed

            // redundant scan
            int T1 = 0, T2 = 0, T3 = 0, p1 = 0, p2 = 0, p3 = 0;
#pragma unroll
            for (int w = 0; w < NWAVE; ++w) {
                const int x = wave_cnt[w][0], y = wave_cnt[w][1], z = wave_cnt[w][2];
                if (w < wv) { p1 += x; p2 += y; p3 += z; }
                T1 += x; T2 += y; T3 += z;
            }
            const int total = T1 + T2 + T3;

            // restage next genome NOW (stays in flight across lgkm barriers)
            if (g < GPB - 1) STAGE_ISSUE(gi + 1);

            if (total <= CAP) {
                int b1 = p1, b2 = T1 + p2, b3 = T1 + T2 + p3;
#define SLOT(J, CI, CO, W) { \
                int k = (int)((keys >> (2*(J))) & 3u); \
                unsigned long long B1 = __ballot(k == 1); \
                unsigned long long B2 = __ballot(k == 2); \
                unsigned long long B3 = __ballot(k == 3); \
                if (k) { \
                    unsigned long long bk = (k == 1) ? B1 : ((k == 2) ? B2 : B3); \
                    int bs = (k == 1) ? b1 : ((k == 2) ? b2 : b3); \
                    int pos = bs + (int)__popcll(bk & lmlt); \
                    edges[pos] = make_uint2(__float_as_uint(W), \
                                            (unsigned)(CI) | ((unsigned)(CO) << 8)); \
                } \
                b1 += (int)__popcll(B1); b2 += (int)__popcll(B2); b3 += (int)__popcll(B3); }
                SLOT(0,  ci0.x, co0.x, w0.x) SLOT(1,  ci0.y, co0.y, w0.y)
                SLOT(2,  ci0.z, co0.z, w0.z) SLOT(3,  ci0.w, co0.w, w0.w)
                SLOT(4,  ci1.x, co1.x, w1.x) SLOT(5,  ci1.y, co1.y, w1.y)
                SLOT(6,  ci1.z, co1.z, w1.z) SLOT(7,  ci1.w, co1.w, w1.w)
                SLOT(8,  ci2.x, co2.x, w2.x) SLOT(9,  ci2.y, co2.y, w2.y)
                SLOT(10, ci2.z, co2.z, w2.z) SLOT(11, ci2.w, co2.w, w2.w)
                SLOT(12, ci3.x, co3.x, w3.x) SLOT(13, ci3.y, co3.y, w3.y)
                SLOT(14, ci3.z, co3.z, w3.z) SLOT(15, ci3.w, co3.w, w3.w)
#undef SLOT
                BAR_LGKM();   // edges ready

#pragma unroll
                for (int L = 1; L <= 3; ++L) {
                    const int sBeg = (L == 1) ? 0  : ((L == 2) ? T1 : T1 + T2);
                    const int sEnd = (L == 1) ? T1 : ((L == 2) ? T1 + T2 : total);
                    for (int p = sBeg + t; p < sEnd; p += NT) {
                        const uint2 ed = edges[p];
                        atomicAdd(&agg[ed.y >> 8], vals[ed.y & 0xFFu] * __uint_as_float(ed.x));
                    }
                    BAR_LGKM();   // adds done
                    if (nlT == L) vals[t] = tanhf(agg[t]);
                    BAR_LGKM();   // updates visible
                }
            } else {
                // fallback (never taken on real data): reg-edge masked atomics
                BAR_LGKM();
#pragma unroll
                for (int L = 1; L <= 3; ++L) {
#define FB(J, CI, CO, W) \
                    if (((keys >> (2*(J))) & 3u) == (unsigned)L) \
                        atomicAdd(&agg[(CO)], vals[(CI)] * (W));
                    FB(0,  ci0.x, co0.x, w0.x) FB(1,  ci0.y, co0.y, w0.y)
                    FB(2,  ci0.z, co0.z, w0.z) FB(3,  ci0.w, co0.w, w0.w)
                    FB(4,  ci1.x, co1.x, w1.x) FB(5,  ci1.y, co1.y, w1.y)
                    FB(6,  ci1.z, co1.z, w1.z) FB(7,  ci1.w, co1.w, w1.w)
                    FB(8,  ci2.x, co2.x, w2.x) FB(9,  ci2.y, co2.y, w2.y)
                    FB(10, ci2.z, co2.z, w2.z) FB(11, ci2.w, co2.w, w2.w)
                    FB(12, ci3.x, co3.x, w3.x) FB(13, ci3.y, co3.y, w3.y)
                    FB(14, ci3.z, co3.z, w3.z) FB(15, ci3.w, co3.w, w3.w)
#undef FB
                    BAR_LGKM();
                    if (nlT == L) vals[t] = tanhf(agg[t]);
                    BAR_LGKM();
                }
            }

            if (t >= NIN && t < NIN + NOUT)
                out[gi * NOUT + (t - NIN)] = vals[t];
        }
#undef STAGE_ISSUE
    } else {
        // ------- slow path (int32 bools; never taken): global streaming -------
#pragma unroll 1
        for (int g = 0; g < GPB; ++g) {
            const size_t gi = g0 + g;
            const int nlT = node_layer[gi * NN + t];
            s_nl[t] = nlT;
            vals[t] = (t < NIN) ? inputs[gi * NIN + t] : 0.0f;
            agg[t]  = 0.0f;
            __syncthreads();
            const int*   en32 = (const int*)conn_en + gi * NE;
            const int*   gci  = conn_in  + gi * NE;
            const int*   gco  = conn_out + gi * NE;
            const float* gw   = conn_w   + gi * NE;
#pragma unroll 1
            for (int L = 1; L <= 3; ++L) {
                for (int e = t; e < NE; e += NT) {
                    if (en32[e]) {
                        const int cc = gco[e];
                        if (s_nl[cc] == L)
                            atomicAdd(&agg[cc], vals[gci[e]] * gw[e]);
                    }
                }
                __syncthreads();
                if (nlT == L) vals[t] = tanhf(agg[t]);
                __syncthreads();
            }
            if (t >= NIN && t < NIN + NOUT)
                out[gi * NOUT + (t - NIN)] = vals[t];
            __syncthreads();
        }
    }
}

extern "C" void kernel_launch(void* const* d_in, const int* in_sizes, int n_in,
                              void* d_out, int out_size, void* d_ws, size_t ws_size,
                              hipStream_t stream) {
    const float* inputs          = (const float*)d_in[0];
    const int*   node_layer      = (const int*)d_in[1];
    const int*   conn_in         = (const int*)d_in[2];
    const int*   conn_out        = (const int*)d_in[3];
    const float* conn_w          = (const float*)d_in[4];
    const unsigned char* conn_en = (const unsigned char*)d_in[5];
    float* out = (float*)d_out;

    const int B = in_sizes[0] / NIN;   // 4096
    neat_fwd<<<B / GPB, NT, 0, stream>>>(inputs, node_layer, conn_in, conn_out,
                                         conn_w, conn_en, out);
}

// Round 12
// 261.550 us; speedup vs baseline: 2.2518x; 2.2518x over previous
//
#include <hip/hip_runtime.h>

// NEAT batched forward — 2 genomes per block, phase-interleaved.
// Evidence R1-R11: VALUBusy*dur ~ const (duty capped ~20%), occupancy doesn't
// move duration, gll staging regressed (R11). Only lever that ever worked:
// more independent work per wave between barriers (R2->R3). So: one block runs
// TWO genomes through every phase back-to-back (independent dep-chains fill
// each other's stall slots; 8 barriers amortized over 2 genomes; 26 vec loads
// in flight at once ~416B/lane). agg needs no per-layer re-zero (buckets are
// per-layer disjoint).

#define NN    256
#define NE    4096
#define NIN   64
#define NOUT  8
#define NT    256
#define NWAVE 4
#define CAP   2560   // per-genome live-edge cap: mean 1536, sd 31 -> 33 sigma

__global__ __launch_bounds__(NT) void neat_fwd(
    const float* __restrict__ inputs,          // [B,64]
    const int*   __restrict__ node_layer,      // [B,256]
    const int*   __restrict__ conn_in,         // [B,4096]
    const int*   __restrict__ conn_out,        // [B,4096]
    const float* __restrict__ conn_w,          // [B,4096]
    const unsigned char* __restrict__ conn_en, // [B,4096] bool (layout sniffed)
    float*       __restrict__ out)             // [B,8]
{
    const int t    = threadIdx.x;
    const int wv   = t >> 6;
    const int lane = t & 63;
    const unsigned long long lmlt = (1ull << lane) - 1ull;
    const size_t giA = (size_t)blockIdx.x * 2;
    const size_t giB = giA + 1;

    __shared__ float          valsA[NN], valsB[NN];
    __shared__ float          aggA[NN],  aggB[NN];
    __shared__ unsigned char  nlA8[NN],  nlB8[NN];
    __shared__ float          ewA[CAP],  ewB[CAP];
    __shared__ unsigned short epA[CAP],  epB[CAP];   // src | (tgt<<8)
    __shared__ int            wcnt[NWAVE][6];        // A:c1,c2,c3  B:c1,c2,c3

    // --- sniff conn_enabled element width (uniform): byte bools vs int32 ---
    const unsigned* en_sniff = (const unsigned*)conn_en;
    bool byte_mode = false;
#pragma unroll
    for (int i = 0; i < 16; ++i) byte_mode |= (en_sniff[i] > 1u);

    // --- init both genomes' LDS state ---
    const int nlA = node_layer[giA * NN + t];
    const int nlB = node_layer[giB * NN + t];
    nlA8[t] = (unsigned char)nlA;
    nlB8[t] = (unsigned char)nlB;
    valsA[t] = (t < NIN) ? inputs[giA * NIN + t] : 0.0f;
    valsB[t] = (t < NIN) ? inputs[giB * NIN + t] : 0.0f;
    aggA[t] = 0.0f;
    aggB[t] = 0.0f;

    // --- load both genomes' edges into NAMED registers (26x16B in flight) ---
    const int4*   ciA4 = (const int4*)(conn_in  + giA * NE);
    const int4*   coA4 = (const int4*)(conn_out + giA * NE);
    const float4* wA4  = (const float4*)(conn_w  + giA * NE);
    const int4*   ciB4 = (const int4*)(conn_in  + giB * NE);
    const int4*   coB4 = (const int4*)(conn_out + giB * NE);
    const float4* wB4  = (const float4*)(conn_w  + giB * NE);

    int4 ciA0 = ciA4[t];        int4 ciA1 = ciA4[NT + t];
    int4 ciA2 = ciA4[2*NT + t]; int4 ciA3 = ciA4[3*NT + t];
    int4 coA0 = coA4[t];        int4 coA1 = coA4[NT + t];
    int4 coA2 = coA4[2*NT + t]; int4 coA3 = coA4[3*NT + t];
    float4 wA0 = wA4[t];        float4 wA1 = wA4[NT + t];
    float4 wA2 = wA4[2*NT + t]; float4 wA3 = wA4[3*NT + t];
    int4 ciB0 = ciB4[t];        int4 ciB1 = ciB4[NT + t];
    int4 ciB2 = ciB4[2*NT + t]; int4 ciB3 = ciB4[3*NT + t];
    int4 coB0 = coB4[t];        int4 coB1 = coB4[NT + t];
    int4 coB2 = coB4[2*NT + t]; int4 coB3 = coB4[3*NT + t];
    float4 wB0 = wB4[t];        float4 wB1 = wB4[NT + t];
    float4 wB2 = wB4[2*NT + t]; float4 wB3 = wB4[3*NT + t];

    unsigned mA = 0, mB = 0;
#define ENMASK(MV, E0, E1, E2, E3) \
    MV = (E0.x?1u<<0:0u)|(E0.y?1u<<1:0u)|(E0.z?1u<<2:0u)|(E0.w?1u<<3:0u) \
       | (E1.x?1u<<4:0u)|(E1.y?1u<<5:0u)|(E1.z?1u<<6:0u)|(E1.w?1u<<7:0u) \
       | (E2.x?1u<<8:0u)|(E2.y?1u<<9:0u)|(E2.z?1u<<10:0u)|(E2.w?1u<<11:0u) \
       | (E3.x?1u<<12:0u)|(E3.y?1u<<13:0u)|(E3.z?1u<<14:0u)|(E3.w?1u<<15:0u);
    if (byte_mode) {
        const uchar4* eA4 = (const uchar4*)(conn_en + giA * NE);
        const uchar4* eB4 = (const uchar4*)(conn_en + giB * NE);
        uchar4 a0 = eA4[t], a1 = eA4[NT+t], a2 = eA4[2*NT+t], a3 = eA4[3*NT+t];
        uchar4 b0 = eB4[t], b1 = eB4[NT+t], b2 = eB4[2*NT+t], b3 = eB4[3*NT+t];
        ENMASK(mA, a0, a1, a2, a3)
        ENMASK(mB, b0, b1, b2, b3)
    } else {
        const int4* eA4 = (const int4*)((const int*)conn_en + giA * NE);
        const int4* eB4 = (const int4*)((const int*)conn_en + giB * NE);
        int4 a0 = eA4[t], a1 = eA4[NT+t], a2 = eA4[2*NT+t], a3 = eA4[3*NT+t];
        int4 b0 = eB4[t], b1 = eB4[NT+t], b2 = eB4[2*NT+t], b3 = eB4[3*NT+t];
        ENMASK(mA, a0, a1, a2, a3)
        ENMASK(mB, b0, b1, b2, b3)
    }
#undef ENMASK
    __syncthreads();   // nl/vals/agg ready

    // --- keys for both genomes (32 independent LDS gathers) ---
    unsigned keysA = 0, keysB = 0;
    int c1A = 0, c2A = 0, c3A = 0, c1B = 0, c2B = 0, c3B = 0;
#define KEYSLOT(MM, NLARR, KEYS, C1, C2, C3, J, CO) { \
    int k = (int)NLARR[(CO)]; \
    k = ((MM >> (J)) & 1u) ? k : 0; \
    KEYS |= (unsigned)k << (2*(J)); \
    C1 += (k == 1); C2 += (k == 2); C3 += (k == 3); }
#define KEYG(MM, NLARR, KEYS, C1, C2, C3, O0, O1, O2, O3) \
    KEYSLOT(MM, NLARR, KEYS, C1, C2, C3, 0,  O0.x) KEYSLOT(MM, NLARR, KEYS, C1, C2, C3, 1,  O0.y) \
    KEYSLOT(MM, NLARR, KEYS, C1, C2, C3, 2,  O0.z) KEYSLOT(MM, NLARR, KEYS, C1, C2, C3, 3,  O0.w) \
    KEYSLOT(MM, NLARR, KEYS, C1, C2, C3, 4,  O1.x) KEYSLOT(MM, NLARR, KEYS, C1, C2, C3, 5,  O1.y) \
    KEYSLOT(MM, NLARR, KEYS, C1, C2, C3, 6,  O1.z) KEYSLOT(MM, NLARR, KEYS, C1, C2, C3, 7,  O1.w) \
    KEYSLOT(MM, NLARR, KEYS, C1, C2, C3, 8,  O2.x) KEYSLOT(MM, NLARR, KEYS, C1, C2, C3, 9,  O2.y) \
    KEYSLOT(MM, NLARR, KEYS, C1, C2, C3, 10, O2.z) KEYSLOT(MM, NLARR, KEYS, C1, C2, C3, 11, O2.w) \
    KEYSLOT(MM, NLARR, KEYS, C1, C2, C3, 12, O3.x) KEYSLOT(MM, NLARR, KEYS, C1, C2, C3, 13, O3.y) \
    KEYSLOT(MM, NLARR, KEYS, C1, C2, C3, 14, O3.z) KEYSLOT(MM, NLARR, KEYS, C1, C2, C3, 15, O3.w)
    KEYG(mA, nlA8, keysA, c1A, c2A, c3A, coA0, coA1, coA2, coA3)
    KEYG(mB, nlB8, keysB, c1B, c2B, c3B, coB0, coB1, coB2, coB3)
#undef KEYG
#undef KEYSLOT

#pragma unroll
    for (int off = 32; off > 0; off >>= 1) {
        c1A += __shfl_down(c1A, off); c2A += __shfl_down(c2A, off); c3A += __shfl_down(c3A, off);
        c1B += __shfl_down(c1B, off); c2B += __shfl_down(c2B, off); c3B += __shfl_down(c3B, off);
    }
    if (lane == 0) {
        wcnt[wv][0] = c1A; wcnt[wv][1] = c2A; wcnt[wv][2] = c3A;
        wcnt[wv][3] = c1B; wcnt[wv][4] = c2B; wcnt[wv][5] = c3B;
    }
    __syncthreads();

    // --- redundant per-thread scans ---
    int T1A = 0, T2A = 0, T3A = 0, p1A = 0, p2A = 0, p3A = 0;
    int T1B = 0, T2B = 0, T3B = 0, p1B = 0, p2B = 0, p3B = 0;
#pragma unroll
    for (int w = 0; w < NWAVE; ++w) {
        const int xa = wcnt[w][0], ya = wcnt[w][1], za = wcnt[w][2];
        const int xb = wcnt[w][3], yb = wcnt[w][4], zb = wcnt[w][5];
        if (w < wv) { p1A += xa; p2A += ya; p3A += za; p1B += xb; p2B += yb; p3B += zb; }
        T1A += xa; T2A += ya; T3A += za; T1B += xb; T2B += yb; T3B += zb;
    }
    const int totalA = T1A + T2A + T3A;
    const int totalB = T1B + T2B + T3B;
    const bool fastA = (totalA <= CAP);
    const bool fastB = (totalB <= CAP);

#define SCAT(KEYS, EW, EP, B1V, B2V, B3V, J, CI, CO, W) { \
    int k = (int)((KEYS >> (2*(J))) & 3u); \
    unsigned long long X1 = __ballot(k == 1); \
    unsigned long long X2 = __ballot(k == 2); \
    unsigned long long X3 = __ballot(k == 3); \
    if (k) { \
        unsigned long long bk = (k == 1) ? X1 : ((k == 2) ? X2 : X3); \
        int bs = (k == 1) ? B1V : ((k == 2) ? B2V : B3V); \
        int pos = bs + (int)__popcll(bk & lmlt); \
        EW[pos] = (W); \
        EP[pos] = (unsigned short)((unsigned)(CI) | ((unsigned)(CO) << 8)); \
    } \
    B1V += (int)__popcll(X1); B2V += (int)__popcll(X2); B3V += (int)__popcll(X3); }
#define SCATG(KEYS, EW, EP, B1V, B2V, B3V, I0, I1, I2, I3, O0, O1, O2, O3, V0, V1, V2, V3) \
    SCAT(KEYS, EW, EP, B1V, B2V, B3V, 0,  I0.x, O0.x, V0.x) SCAT(KEYS, EW, EP, B1V, B2V, B3V, 1,  I0.y, O0.y, V0.y) \
    SCAT(KEYS, EW, EP, B1V, B2V, B3V, 2,  I0.z, O0.z, V0.z) SCAT(KEYS, EW, EP, B1V, B2V, B3V, 3,  I0.w, O0.w, V0.w) \
    SCAT(KEYS, EW, EP, B1V, B2V, B3V, 4,  I1.x, O1.x, V1.x) SCAT(KEYS, EW, EP, B1V, B2V, B3V, 5,  I1.y, O1.y, V1.y) \
    SCAT(KEYS, EW, EP, B1V, B2V, B3V, 6,  I1.z, O1.z, V1.z) SCAT(KEYS, EW, EP, B1V, B2V, B3V, 7,  I1.w, O1.w, V1.w) \
    SCAT(KEYS, EW, EP, B1V, B2V, B3V, 8,  I2.x, O2.x, V2.x) SCAT(KEYS, EW, EP, B1V, B2V, B3V, 9,  I2.y, O2.y, V2.y) \
    SCAT(KEYS, EW, EP, B1V, B2V, B3V, 10, I2.z, O2.z, V2.z) SCAT(KEYS, EW, EP, B1V, B2V, B3V, 11, I2.w, O2.w, V2.w) \
    SCAT(KEYS, EW, EP, B1V, B2V, B3V, 12, I3.x, O3.x, V3.x) SCAT(KEYS, EW, EP, B1V, B2V, B3V, 13, I3.y, O3.y, V3.y) \
    SCAT(KEYS, EW, EP, B1V, B2V, B3V, 14, I3.z, O3.z, V3.z) SCAT(KEYS, EW, EP, B1V, B2V, B3V, 15, I3.w, O3.w, V3.w)

    if (fastA) {
        int b1 = p1A, b2 = T1A + p2A, b3 = T1A + T2A + p3A;
        SCATG(keysA, ewA, epA, b1, b2, b3,
              ciA0, ciA1, ciA2, ciA3, coA0, coA1, coA2, coA3, wA0, wA1, wA2, wA3)
    }
    if (fastB) {
        int b1 = p1B, b2 = T1B + p2B, b3 = T1B + T2B + p3B;
        SCATG(keysB, ewB, epB, b1, b2, b3,
              ciB0, ciB1, ciB2, ciB3, coB0, coB1, coB2, coB3, wB0, wB1, wB2, wB3)
    }
#undef SCATG
#undef SCAT
    __syncthreads();   // edges ready

    // --- streaming fallback for a genome whose buckets overflowed (never on real data) ---
#define STREAM_LAYER(GI, NLARR, AGG, VALS, L) { \
    const int*   gci = conn_in  + (GI) * NE; \
    const int*   gco = conn_out + (GI) * NE; \
    const float* gw  = conn_w   + (GI) * NE; \
    for (int e = t; e < NE; e += NT) { \
        const bool en = byte_mode ? (conn_en[(GI)*NE + e] != 0) \
                                  : (((const int*)conn_en)[(GI)*NE + e] != 0); \
        if (en) { \
            const int cc = gco[e]; \
            if ((int)NLARR[cc] == (L)) atomicAdd(&AGG[cc], VALS[gci[e]] * gw[e]); \
        } \
    } }

    // --- 3 layer passes, A and B interleaved; no agg re-zero needed ---
#pragma unroll
    for (int L = 1; L <= 3; ++L) {
        if (fastA) {
            const int sBeg = (L == 1) ? 0   : ((L == 2) ? T1A : T1A + T2A);
            const int sEnd = (L == 1) ? T1A : ((L == 2) ? T1A + T2A : totalA);
            for (int p = sBeg + t; p < sEnd; p += NT) {
                const unsigned pk = epA[p];
                atomicAdd(&aggA[pk >> 8], valsA[pk & 0xFFu] * ewA[p]);
            }
        } else {
            STREAM_LAYER(giA, nlA8, aggA, valsA, L)
        }
        if (fastB) {
            const int sBeg = (L == 1) ? 0   : ((L == 2) ? T1B : T1B + T2B);
            const int sEnd = (L == 1) ? T1B : ((L == 2) ? T1B + T2B : totalB);
            for (int p = sBeg + t; p < sEnd; p += NT) {
                const unsigned pk = epB[p];
                atomicAdd(&aggB[pk >> 8], valsB[pk & 0xFFu] * ewB[p]);
            }
        } else {
            STREAM_LAYER(giB, nlB8, aggB, valsB, L)
        }
        __syncthreads();   // adds done
        if (nlA == L) valsA[t] = tanhf(aggA[t]);
        if (nlB == L) valsB[t] = tanhf(aggB[t]);
        if (L < 3) __syncthreads();   // updates visible for next gathers
    }
#undef STREAM_LAYER

    // vals[t] only ever written by thread t -> no final barrier needed
    if (t >= NIN && t < NIN + NOUT) {
        out[giA * NOUT + (t - NIN)] = valsA[t];
        out[giB * NOUT + (t - NIN)] = valsB[t];
    }
}

extern "C" void kernel_launch(void* const* d_in, const int* in_sizes, int n_in,
                              void* d_out, int out_size, void* d_ws, size_t ws_size,
                              hipStream_t stream) {
    const float* inputs          = (const float*)d_in[0];
    const int*   node_layer      = (const int*)d_in[1];
    const int*   conn_in         = (const int*)d_in[2];
    const int*   conn_out        = (const int*)d_in[3];
    const float* conn_w          = (const float*)d_in[4];
    const unsigned char* conn_en = (const unsigned char*)d_in[5];
    float* out = (float*)d_out;

    const int B = in_sizes[0] / NIN;   // 4096
    neat_fwd<<<B / 2, NT, 0, stream>>>(inputs, node_layer, conn_in, conn_out,
                                       conn_w, conn_en, out);
}